// Round 5
// baseline (962.304 us; speedup 1.0000x reference)
//
#include <hip/hip_runtime.h>
#include <hip/hip_bf16.h>

// GCN forward — bucketed counting-sort CSR + LDS-accumulated gather aggregation.
// No global atomics anywhere. N=100000, E=3200000, IN_C=128, HID=16, OUT=1.

constexpr int N_NODES = 100000;
constexpr int N_EDGES = 3200000;
constexpr int INC = 128;
constexpr int HID = 16;

constexpr int BSH  = 128;                       // nodes per bucket
constexpr int NBUK = (N_NODES + BSH - 1) / BSH; // 782
constexpr int NBLK = 256;                       // histogram blocks
constexpr int EPB  = N_EDGES / NBLK;            // 12500 edges per block (exact)

// ---------------- pass 1: per-block LDS histogram + local rank ----------------

__global__ __launch_bounds__(256) void k_hist1(const int* __restrict__ col,
                                               int* __restrict__ rank,
                                               int* __restrict__ blkhist) {
    __shared__ int lh[NBUK];
    int tid = threadIdx.x, blk = blockIdx.x;
    for (int i = tid; i < NBUK; i += 256) lh[i] = 0;
    __syncthreads();
    int s = blk * EPB, e2 = s + EPB;
    for (int e = s + tid; e < e2; e += 256) {
        int b = col[e] >> 7;
        rank[e] = atomicAdd(&lh[b], 1);          // LDS atomic (fast)
    }
    __syncthreads();
    for (int i = tid; i < NBUK; i += 256) blkhist[i * NBLK + blk] = lh[i];
}

// ---------------- pass 2a: per-bucket scan over the 256 block counts ----------

__global__ __launch_bounds__(256) void k_colscan(const int* __restrict__ blkhist,
                                                 int* __restrict__ offs,
                                                 int* __restrict__ total) {
    __shared__ int s[NBLK];
    int b = blockIdx.x, t = threadIdx.x;
    int v = blkhist[b * NBLK + t];
    s[t] = v;
    __syncthreads();
    for (int off = 1; off < NBLK; off <<= 1) {
        int u = (t >= off) ? s[t - off] : 0;
        __syncthreads();
        s[t] += u;
        __syncthreads();
    }
    offs[b * NBLK + t] = s[t] - v;               // exclusive over blocks
    if (t == NBLK - 1) total[b] = s[NBLK - 1];
}

// ---------------- pass 2b: bucket starts (single block) ----------------

__global__ __launch_bounds__(1024) void k_bscan(const int* __restrict__ total,
                                                int* __restrict__ bstart) {
    __shared__ int s[1024];
    int t = threadIdx.x;
    int v = (t < NBUK) ? total[t] : 0;
    s[t] = v;
    __syncthreads();
    for (int off = 1; off < 1024; off <<= 1) {
        int u = (t >= off) ? s[t - off] : 0;
        __syncthreads();
        s[t] += u;
        __syncthreads();
    }
    if (t <= NBUK) bstart[t] = s[t] - v;         // bstart[NBUK] = E
}

// ---------------- pass 3: placement (contiguous-run scattered stores) ---------

__global__ __launch_bounds__(256) void k_place(const int* __restrict__ row,
                                               const int* __restrict__ col,
                                               const float* __restrict__ ew,
                                               const int* __restrict__ rank,
                                               const int* __restrict__ offs,
                                               const int* __restrict__ bstart,
                                               int2* __restrict__ pay) {
    int tid = threadIdx.x, blk = blockIdx.x;
    int s = blk * EPB, e2 = s + EPB;
    for (int e = s + tid; e < e2; e += 256) {
        int c = col[e];
        int b = c >> 7, dlow = c & 127;
        int p = bstart[b] + offs[b * NBLK + blk] + rank[e];
        pay[p] = make_int2((dlow << 17) | row[e], __float_as_int(ew[e]));
    }
}

// ---------------- degree -> dinv (block per bucket, LDS accumulate) -----------

__global__ __launch_bounds__(256) void k_deg(const int* __restrict__ bstart,
                                             const int2* __restrict__ pay,
                                             float* __restrict__ dinv) {
    __shared__ float da[BSH];
    int b = blockIdx.x, t = threadIdx.x;
    if (t < BSH) da[t] = 1.0f;                   // self-loop weight
    __syncthreads();
    int s = bstart[b], e2 = bstart[b + 1];
    for (int p = s + t; p < e2; p += 256) {
        int2 pr = pay[p];
        atomicAdd(&da[pr.x >> 17], __int_as_float(pr.y));
    }
    __syncthreads();
    int node = b * BSH + t;
    if (t < BSH && node < N_NODES) dinv[node] = rsqrtf(da[t]);
}

// ---------------- GEMM x@W1, epilogue x dinv: t1 = dinv ⊙ (x@W1) --------------

__global__ __launch_bounds__(256) void k_gemm_in(const float* __restrict__ x,
                                                 const float* __restrict__ W1,
                                                 const float* __restrict__ dinv,
                                                 float* __restrict__ t1) {
    __shared__ float ws[INC * HID];      // 2048
    __shared__ float xs[16 * 129];       // padded rows: bank-conflict-free
    int tid = threadIdx.x;
    int nb = blockIdx.x * 16;
    const float4* x4 = (const float4*)(x + (size_t)nb * INC);
    for (int j = tid; j < 512; j += 256) {
        float4 v = x4[j];
        int n = j >> 5, kq = (j & 31) << 2;
        float* d = &xs[n * 129 + kq];
        d[0] = v.x; d[1] = v.y; d[2] = v.z; d[3] = v.w;
    }
    for (int j = tid; j < 512; j += 256)
        ((float4*)ws)[j] = ((const float4*)W1)[j];
    __syncthreads();
    int ln = tid >> 4, c = tid & 15;
    float acc = 0.f;
#pragma unroll
    for (int k = 0; k < INC; ++k) acc += xs[ln * 129 + k] * ws[k * HID + c];
    int node = nb + ln;
    t1[(node << 4) + c] = dinv[node] * acc;
}

// ---------------- layer-1 aggregation + bias + relu + (h@W2)*dinv -> t2 -------
// block per bucket; acc[128][16] in LDS (stride 17).

__global__ __launch_bounds__(256) void k_agg_mid(const int* __restrict__ bstart,
                                                 const int2* __restrict__ pay,
                                                 const float* __restrict__ dinv,
                                                 const float* __restrict__ t1,
                                                 const float* __restrict__ bias,
                                                 const float* __restrict__ W2,
                                                 float* __restrict__ t2) {
    __shared__ float acc[BSH * 17];
    __shared__ float w2s[HID * HID];
    int b = blockIdx.x, tid = threadIdx.x;
    w2s[tid & 255] = W2[tid & 255];
    for (int i = tid; i < BSH * 17; i += 256) acc[i] = 0.f;
    __syncthreads();
    int s = bstart[b], e2 = bstart[b + 1];
    int g = tid >> 4, c = tid & 15;
    int p = s + g;
    for (; p + 48 < e2; p += 64) {
        int2 a0 = pay[p], a1 = pay[p + 16], a2 = pay[p + 32], a3 = pay[p + 48];
        float v0 = t1[((a0.x & 0x1FFFF) << 4) + c] * __int_as_float(a0.y);
        float v1 = t1[((a1.x & 0x1FFFF) << 4) + c] * __int_as_float(a1.y);
        float v2 = t1[((a2.x & 0x1FFFF) << 4) + c] * __int_as_float(a2.y);
        float v3 = t1[((a3.x & 0x1FFFF) << 4) + c] * __int_as_float(a3.y);
        atomicAdd(&acc[(a0.x >> 17) * 17 + c], v0);
        atomicAdd(&acc[(a1.x >> 17) * 17 + c], v1);
        atomicAdd(&acc[(a2.x >> 17) * 17 + c], v2);
        atomicAdd(&acc[(a3.x >> 17) * 17 + c], v3);
    }
    for (; p < e2; p += 16) {
        int2 a0 = pay[p];
        float v0 = t1[((a0.x & 0x1FFFF) << 4) + c] * __int_as_float(a0.y);
        atomicAdd(&acc[(a0.x >> 17) * 17 + c], v0);
    }
    __syncthreads();
    int node0 = b * BSH;
    // h = relu(dinv*(acc + t1_self) + bias)  (in registers)
    float rv[8];
#pragma unroll
    for (int i = 0; i < 8; ++i) {
        int idx = tid + i * 256;
        int n = idx >> 4, c2 = idx & 15;
        int node = node0 + n;
        rv[i] = 0.f;
        if (node < N_NODES)
            rv[i] = fmaxf(dinv[node] * (acc[n * 17 + c2] + t1[(node << 4) + c2]) + bias[c2], 0.f);
    }
    __syncthreads();
#pragma unroll
    for (int i = 0; i < 8; ++i) {
        int idx = tid + i * 256;
        acc[(idx >> 4) * 17 + (idx & 15)] = rv[i];
    }
    __syncthreads();
    // t2 = dinv ⊙ (h @ W2)
#pragma unroll
    for (int i = 0; i < 8; ++i) {
        int idx = tid + i * 256;
        int n = idx >> 4, c2 = idx & 15;
        int node = node0 + n;
        if (node < N_NODES) {
            float s2 = 0.f;
#pragma unroll
            for (int k = 0; k < HID; ++k) s2 += acc[n * 17 + k] * w2s[k * HID + c2];
            t2[(node << 4) + c2] = dinv[node] * s2;
        }
    }
}

// ---------------- layer-2 aggregation + bias + relu + Wout dot -> out ---------

__global__ __launch_bounds__(256) void k_agg_out(const int* __restrict__ bstart,
                                                 const int2* __restrict__ pay,
                                                 const float* __restrict__ dinv,
                                                 const float* __restrict__ t2,
                                                 const float* __restrict__ bias,
                                                 const float* __restrict__ Wout,
                                                 const float* __restrict__ bout,
                                                 float* __restrict__ out) {
    __shared__ float acc[BSH * 17];
    int b = blockIdx.x, tid = threadIdx.x;
    for (int i = tid; i < BSH * 17; i += 256) acc[i] = 0.f;
    __syncthreads();
    int s = bstart[b], e2 = bstart[b + 1];
    int g = tid >> 4, c = tid & 15;
    int p = s + g;
    for (; p + 48 < e2; p += 64) {
        int2 a0 = pay[p], a1 = pay[p + 16], a2 = pay[p + 32], a3 = pay[p + 48];
        float v0 = t2[((a0.x & 0x1FFFF) << 4) + c] * __int_as_float(a0.y);
        float v1 = t2[((a1.x & 0x1FFFF) << 4) + c] * __int_as_float(a1.y);
        float v2 = t2[((a2.x & 0x1FFFF) << 4) + c] * __int_as_float(a2.y);
        float v3 = t2[((a3.x & 0x1FFFF) << 4) + c] * __int_as_float(a3.y);
        atomicAdd(&acc[(a0.x >> 17) * 17 + c], v0);
        atomicAdd(&acc[(a1.x >> 17) * 17 + c], v1);
        atomicAdd(&acc[(a2.x >> 17) * 17 + c], v2);
        atomicAdd(&acc[(a3.x >> 17) * 17 + c], v3);
    }
    for (; p < e2; p += 16) {
        int2 a0 = pay[p];
        float v0 = t2[((a0.x & 0x1FFFF) << 4) + c] * __int_as_float(a0.y);
        atomicAdd(&acc[(a0.x >> 17) * 17 + c], v0);
    }
    __syncthreads();
    int node0 = b * BSH;
    int n = tid >> 4, c2 = tid & 15;
    float wout = Wout[c2], bo = bout[0];
#pragma unroll
    for (int i = 0; i < 8; ++i) {
        int nn = n + i * 16;
        int node = node0 + nn;
        float r = 0.f;
        if (node < N_NODES) {
            float v = dinv[node] * (acc[nn * 17 + c2] + t2[(node << 4) + c2]) + bias[c2];
            r = fmaxf(v, 0.f) * wout;
        }
        r += __shfl_xor(r, 1);
        r += __shfl_xor(r, 2);
        r += __shfl_xor(r, 4);
        r += __shfl_xor(r, 8);
        if (c2 == 0 && node < N_NODES) out[node] = r + bo;
    }
}

extern "C" void kernel_launch(void* const* d_in, const int* in_sizes, int n_in,
                              void* d_out, int out_size, void* d_ws, size_t ws_size,
                              hipStream_t stream) {
    const float* x    = (const float*)d_in[0];
    const int*   eidx = (const int*)d_in[1];
    const float* ew   = (const float*)d_in[2];
    const float* W1   = (const float*)d_in[5];
    const float* b1   = (const float*)d_in[6];
    const float* W2   = (const float*)d_in[7];
    const float* b2   = (const float*)d_in[8];
    const float* Wout = (const float*)d_in[9];
    const float* bout = (const float*)d_in[10];
    float* out = (float*)d_out;

    const int* row = eidx;             // edge_index[0] (src)
    const int* col = eidx + N_EDGES;   // edge_index[1] (dst)

    // workspace (4B units)
    int*   rank    = (int*)d_ws;                    // E       (dead after place)
    float* t1      = (float*)rank;                  // N*16    (aliases rank)
    float* t2      = t1 + (size_t)N_NODES * HID;    // N*16    (aliases rank)
    int*   blkhist = rank + N_EDGES;                // NBUK*NBLK = 200192
    int*   offs    = blkhist + NBUK * NBLK;         // 200192
    int*   total   = offs + NBUK * NBLK;            // 784
    int*   bstart  = total + 784;                   // 784
    float* dinv    = (float*)(bstart + 784);        // N
    int2*  pay     = (int2*)(dinv + N_NODES);       // E int2 (offset even -> 8B aligned)

    const int B = 256;

    // CSR build (bucket-level)
    k_hist1  <<<NBLK, B, 0, stream>>>(col, rank, blkhist);
    k_colscan<<<NBUK, B, 0, stream>>>(blkhist, offs, total);
    k_bscan  <<<1, 1024, 0, stream>>>(total, bstart);
    k_place  <<<NBLK, B, 0, stream>>>(row, col, ew, rank, offs, bstart, pay);

    // normalization
    k_deg<<<NBUK, B, 0, stream>>>(bstart, pay, dinv);

    // layer 1 GEMM (+dinv epilogue)
    k_gemm_in<<<N_NODES / 16, B, 0, stream>>>(x, W1, dinv, t1);

    // layer 1 aggregation + relu + fused h@W2 (+dinv epilogue)
    k_agg_mid<<<NBUK, B, 0, stream>>>(bstart, pay, dinv, t1, b1, W2, t2);

    // layer 2 aggregation + relu + fused output projection
    k_agg_out<<<NBUK, B, 0, stream>>>(bstart, pay, dinv, t2, b2, Wout, bout, out);
}

// Round 6
// 483.065 us; speedup vs baseline: 1.9921x; 1.9921x over previous
//
#include <hip/hip_runtime.h>
#include <hip/hip_bf16.h>

// GCN forward — two-level counting-sort CSR (no global atomics) +
// wave-per-node gather aggregation.
// N=100000, E=3200000, IN_C=128, HID=16, OUT=1.

constexpr int N_NODES = 100000;
constexpr int N_EDGES = 3200000;
constexpr int INC = 128;
constexpr int HID = 16;

constexpr int BSH  = 128;                       // nodes per bucket
constexpr int NBUK = (N_NODES + BSH - 1) / BSH; // 782
constexpr int NBLK = 256;                       // histogram blocks
constexpr int EPB  = N_EDGES / NBLK;            // 12500 edges/block (exact)
constexpr int BUFCAP = 6144;                    // LDS edge staging (32 sigma margin)

// ---------------- pass 1: per-block LDS histogram + local rank ----------------

__global__ __launch_bounds__(256) void k_hist1(const int* __restrict__ col,
                                               int* __restrict__ rank,
                                               int* __restrict__ blkhist) {
    __shared__ int lh[NBUK];
    int tid = threadIdx.x, blk = blockIdx.x;
    for (int i = tid; i < NBUK; i += 256) lh[i] = 0;
    __syncthreads();
    int s = blk * EPB, e2 = s + EPB;
    for (int e = s + tid; e < e2; e += 256) {
        int b = col[e] >> 7;
        rank[e] = atomicAdd(&lh[b], 1);          // LDS atomic
    }
    __syncthreads();
    for (int i = tid; i < NBUK; i += 256) blkhist[i * NBLK + blk] = lh[i];
}

// ---------------- pass 2a: per-bucket scan over the 256 block counts ----------

__global__ __launch_bounds__(256) void k_colscan(const int* __restrict__ blkhist,
                                                 int* __restrict__ offs,
                                                 int* __restrict__ total) {
    __shared__ int s[NBLK];
    int b = blockIdx.x, t = threadIdx.x;
    int v = blkhist[b * NBLK + t];
    s[t] = v;
    __syncthreads();
    for (int off = 1; off < NBLK; off <<= 1) {
        int u = (t >= off) ? s[t - off] : 0;
        __syncthreads();
        s[t] += u;
        __syncthreads();
    }
    offs[b * NBLK + t] = s[t] - v;
    if (t == NBLK - 1) total[b] = s[NBLK - 1];
}

// ---------------- pass 2b: bucket starts (single block) ----------------

__global__ __launch_bounds__(1024) void k_bscan(const int* __restrict__ total,
                                                int* __restrict__ bstart) {
    __shared__ int s[1024];
    int t = threadIdx.x;
    int v = (t < NBUK) ? total[t] : 0;
    s[t] = v;
    __syncthreads();
    for (int off = 1; off < 1024; off <<= 1) {
        int u = (t >= off) ? s[t - off] : 0;
        __syncthreads();
        s[t] += u;
        __syncthreads();
    }
    if (t <= NBUK) bstart[t] = s[t] - v;         // bstart[NBUK] = E
}

// ---------------- pass 3: bucket-level placement ----------------

__global__ __launch_bounds__(256) void k_place(const int* __restrict__ row,
                                               const int* __restrict__ col,
                                               const float* __restrict__ ew,
                                               const int* __restrict__ rank,
                                               const int* __restrict__ offs,
                                               const int* __restrict__ bstart,
                                               int2* __restrict__ pay) {
    int tid = threadIdx.x, blk = blockIdx.x;
    int s = blk * EPB, e2 = s + EPB;
    for (int e = s + tid; e < e2; e += 256) {
        int c = col[e];
        int b = c >> 7, dlow = c & 127;
        int p = bstart[b] + offs[b * NBLK + blk] + rank[e];
        pay[p] = make_int2((dlow << 17) | row[e], __float_as_int(ew[e]));
    }
}

// ---------------- pass 4: in-bucket node sort (in place) + node_start + dinv --

__global__ __launch_bounds__(256) void k_sort2(const int* __restrict__ bstart,
                                               int2* __restrict__ pay,
                                               int* __restrict__ node_start,
                                               float* __restrict__ dinv) {
    __shared__ int2 buf[BUFCAP];
    __shared__ int cnt[BSH], sc[BSH], pos[BSH];
    __shared__ float dsum[BSH];
    int b = blockIdx.x, t = threadIdx.x;
    if (t < BSH) { cnt[t] = 0; dsum[t] = 1.0f; }   // 1.0 = self-loop weight
    __syncthreads();
    int s = bstart[b], e2 = bstart[b + 1];
    int m = e2 - s;                                 // <= BUFCAP (32-sigma)
    for (int j = t; j < m; j += 256) {
        int2 pr = pay[s + j];
        buf[j] = pr;
        int d = pr.x >> 17;
        atomicAdd(&cnt[d], 1);
        atomicAdd(&dsum[d], __int_as_float(pr.y));
    }
    __syncthreads();
    int v = (t < BSH) ? cnt[t] : 0;
    if (t < BSH) sc[t] = v;
    __syncthreads();
    for (int off = 1; off < BSH; off <<= 1) {
        int u = (t >= off && t < BSH) ? sc[t - off] : 0;
        __syncthreads();
        if (t < BSH) sc[t] += u;
        __syncthreads();
    }
    if (t < BSH) {
        int excl = sc[t] - v;
        pos[t] = excl;
        int node = b * BSH + t;
        if (node <= N_NODES) node_start[node] = s + excl;  // node==N -> E sentinel
        if (node < N_NODES) dinv[node] = rsqrtf(dsum[t]);
    }
    __syncthreads();
    for (int j = t; j < m; j += 256) {
        int2 pr = buf[j];
        int q = atomicAdd(&pos[pr.x >> 17], 1);
        pay[s + q] = make_int2(pr.x & 0x1FFFF, pr.y);     // strip dlow
    }
}

// ---------------- GEMM x@W1, epilogue x dinv: t1 = dinv ⊙ (x@W1) --------------

__global__ __launch_bounds__(256) void k_gemm_in(const float* __restrict__ x,
                                                 const float* __restrict__ W1,
                                                 const float* __restrict__ dinv,
                                                 float* __restrict__ t1) {
    __shared__ float ws[INC * HID];      // 2048
    __shared__ float xs[16 * 129];       // padded rows
    int tid = threadIdx.x;
    int nb = blockIdx.x * 16;
    const float4* x4 = (const float4*)(x + (size_t)nb * INC);
    for (int j = tid; j < 512; j += 256) {
        float4 v = x4[j];
        int n = j >> 5, kq = (j & 31) << 2;
        float* d = &xs[n * 129 + kq];
        d[0] = v.x; d[1] = v.y; d[2] = v.z; d[3] = v.w;
    }
    for (int j = tid; j < 512; j += 256)
        ((float4*)ws)[j] = ((const float4*)W1)[j];
    __syncthreads();
    int ln = tid >> 4, c = tid & 15;
    float acc = 0.f;
#pragma unroll
    for (int k = 0; k < INC; ++k) acc += xs[ln * 129 + k] * ws[k * HID + c];
    int node = nb + ln;
    t1[(node << 4) + c] = dinv[node] * acc;
}

// ---------------- aggregation, one wave per node ----------------
// lanes = 4 edge-slots x 16 channels. h = relu(dinv[i]*(acc + t1[i][c]) + b[c])

__global__ __launch_bounds__(256) void k_agg_mid(const int* __restrict__ node_start,
                                                 const int2* __restrict__ pay,
                                                 const float* __restrict__ dinv,
                                                 const float* __restrict__ t1,
                                                 const float* __restrict__ b,
                                                 float* __restrict__ h) {
    int i = (blockIdx.x * 256 + threadIdx.x) >> 6;
    if (i >= N_NODES) return;
    int lane = threadIdx.x & 63;
    int eo = lane >> 4;       // 0..3
    int c  = lane & 15;
    int s = node_start[i], e2 = node_start[i + 1];
    float acc = 0.f;
    for (int p = s + eo; p < e2; p += 4) {
        int2 pr = pay[p];
        acc += __int_as_float(pr.y) * t1[((size_t)pr.x << 4) + c];
    }
    acc += __shfl_xor(acc, 16);
    acc += __shfl_xor(acc, 32);
    float v = dinv[i] * (acc + t1[((size_t)i << 4) + c]) + b[c];
    if (lane < 16) h[((size_t)i << 4) + c] = fmaxf(v, 0.f);
}

// layer-2 variant: fuse bias+relu+output projection, write out[i] directly.

__global__ __launch_bounds__(256) void k_agg_out(const int* __restrict__ node_start,
                                                 const int2* __restrict__ pay,
                                                 const float* __restrict__ dinv,
                                                 const float* __restrict__ t2,
                                                 const float* __restrict__ b,
                                                 const float* __restrict__ Wout,
                                                 const float* __restrict__ bout,
                                                 float* __restrict__ out) {
    int i = (blockIdx.x * 256 + threadIdx.x) >> 6;
    if (i >= N_NODES) return;
    int lane = threadIdx.x & 63;
    int eo = lane >> 4;
    int c  = lane & 15;
    int s = node_start[i], e2 = node_start[i + 1];
    float acc = 0.f;
    for (int p = s + eo; p < e2; p += 4) {
        int2 pr = pay[p];
        acc += __int_as_float(pr.y) * t2[((size_t)pr.x << 4) + c];
    }
    acc += __shfl_xor(acc, 16);
    acc += __shfl_xor(acc, 32);
    float v = dinv[i] * (acc + t2[((size_t)i << 4) + c]) + b[c];
    float r = fmaxf(v, 0.f) * Wout[c];
#pragma unroll
    for (int m = 8; m >= 1; m >>= 1) r += __shfl_xor(r, m);
    if (lane == 0) out[i] = r + bout[0];
}

// ---------------- GEMM h@W2, epilogue x dinv ----------------

__global__ __launch_bounds__(256) void k_gemm_hid(const float* __restrict__ h,
                                                  const float* __restrict__ W,
                                                  const float* __restrict__ dinv,
                                                  float* __restrict__ t2) {
    __shared__ float ws[HID * HID];
    int tid = threadIdx.x;
    if (tid < HID * HID) ws[tid] = W[tid];
    __syncthreads();
    int idx = blockIdx.x * 256 + tid;
    if (idx >= N_NODES * HID) return;
    int i = idx >> 4, c = idx & 15;
    const float* hr = h + (size_t)i * HID;
    float acc = 0.f;
#pragma unroll
    for (int k = 0; k < HID; ++k) acc += hr[k] * ws[k * HID + c];
    t2[idx] = dinv[i] * acc;
}

extern "C" void kernel_launch(void* const* d_in, const int* in_sizes, int n_in,
                              void* d_out, int out_size, void* d_ws, size_t ws_size,
                              hipStream_t stream) {
    const float* x    = (const float*)d_in[0];
    const int*   eidx = (const int*)d_in[1];
    const float* ew   = (const float*)d_in[2];
    const float* W1   = (const float*)d_in[5];
    const float* b1   = (const float*)d_in[6];
    const float* W2   = (const float*)d_in[7];
    const float* b2   = (const float*)d_in[8];
    const float* Wout = (const float*)d_in[9];
    const float* bout = (const float*)d_in[10];
    float* out = (float*)d_out;

    const int* row = eidx;             // edge_index[0] (src)
    const int* col = eidx + N_EDGES;   // edge_index[1] (dst)

    // workspace (4B units)
    int*   rank    = (int*)d_ws;                     // E (dead after k_place)
    float* t1      = (float*)rank;                   // N*16 (aliases rank; t2 reuses)
    float* h       = t1 + (size_t)N_NODES * HID;     // N*16 (aliases rank)
    int*   blkhist = rank + N_EDGES;                 // NBUK*NBLK = 200192
    int*   offs    = blkhist + NBUK * NBLK;          // 200192
    int*   total   = offs + NBUK * NBLK;             // 784
    int*   bstart  = total + 784;                    // 784
    float* dinv    = (float*)(bstart + 784);         // N
    int*   nstart  = (int*)(dinv + N_NODES);         // N+2 (padded even)
    int2*  pay     = (int2*)(nstart + N_NODES + 2);  // E int2 (8B-aligned offset)

    float* t2 = t1;                                  // gemm_hid overwrites t1

    const int B = 256;
    const int gW = (N_NODES * 64 + B - 1) / B;       // 25000 (wave per node)

    // CSR build (two-level counting sort, no global atomics)
    k_hist1  <<<NBLK, B, 0, stream>>>(col, rank, blkhist);
    k_colscan<<<NBUK, B, 0, stream>>>(blkhist, offs, total);
    k_bscan  <<<1, 1024, 0, stream>>>(total, bstart);
    k_place  <<<NBLK, B, 0, stream>>>(row, col, ew, rank, offs, bstart, pay);
    k_sort2  <<<NBUK, B, 0, stream>>>(bstart, pay, nstart, dinv);

    // layer 1
    k_gemm_in<<<N_NODES / 16, B, 0, stream>>>(x, W1, dinv, t1);
    k_agg_mid<<<gW, B, 0, stream>>>(nstart, pay, dinv, t1, b1, h);

    // layer 2 (+ fused output projection)
    k_gemm_hid<<<(N_NODES * HID + B - 1) / B, B, 0, stream>>>(h, W2, dinv, t2);
    k_agg_out<<<gW, B, 0, stream>>>(nstart, pay, dinv, t2, b2, Wout, bout, out);
}

// Round 7
// 434.219 us; speedup vs baseline: 2.2162x; 1.1125x over previous
//
#include <hip/hip_runtime.h>
#include <hip/hip_bf16.h>

// GCN forward — two-level counting-sort CSR (no global atomics, coalesced
// placement) + wave-per-node gather aggregation.
// N=100000, E=3200000, IN_C=128, HID=16, OUT=1.

constexpr int N_NODES = 100000;
constexpr int N_EDGES = 3200000;
constexpr int INC = 128;
constexpr int HID = 16;

constexpr int BSH  = 128;                       // nodes per bucket
constexpr int NBUK = (N_NODES + BSH - 1) / BSH; // 782
constexpr int NBLK = 1024;                      // edge-chunk blocks
constexpr int EPB  = N_EDGES / NBLK;            // 3125 edges/block (exact)
constexpr int BUFCAP = 6144;                    // LDS edge staging in sort2

// ---------------- pass 1: per-block LDS histogram (block-major out) -----------

__global__ __launch_bounds__(256) void k_hist1(const int* __restrict__ col,
                                               int* __restrict__ blkhist) {
    __shared__ int lh[NBUK];
    int tid = threadIdx.x, blk = blockIdx.x;
    for (int i = tid; i < NBUK; i += 256) lh[i] = 0;
    __syncthreads();
    int s = blk * EPB;
    for (int e = s + tid; e < s + EPB; e += 256)
        atomicAdd(&lh[col[e] >> 7], 1);          // LDS atomic
    __syncthreads();
    for (int i = tid; i < NBUK; i += 256)
        blkhist[blk * NBUK + i] = lh[i];         // coalesced
}

// ---------------- pass 2a: per-bucket scan over the 1024 block counts ---------

__global__ __launch_bounds__(1024) void k_colscan(const int* __restrict__ blkhist,
                                                  int* __restrict__ offs,
                                                  int* __restrict__ total) {
    __shared__ int sA[NBLK], sB[NBLK];
    int b = blockIdx.x, t = threadIdx.x;
    int v = blkhist[t * NBUK + b];               // strided read (L2-shared)
    sA[t] = v;
    __syncthreads();
    int* src = sA; int* dst = sB;
    for (int off = 1; off < NBLK; off <<= 1) {
        dst[t] = src[t] + ((t >= off) ? src[t - off] : 0);
        __syncthreads();
        int* tmp = src; src = dst; dst = tmp;
    }
    offs[b * NBLK + t] = src[t] - v;             // exclusive, coalesced write
    if (t == NBLK - 1) total[b] = src[NBLK - 1];
}

// ---------------- pass 2b: bucket starts (single block) ----------------

__global__ __launch_bounds__(1024) void k_bscan(const int* __restrict__ total,
                                                int* __restrict__ bstart) {
    __shared__ int s[1024];
    int t = threadIdx.x;
    int v = (t < NBUK) ? total[t] : 0;
    s[t] = v;
    __syncthreads();
    for (int off = 1; off < 1024; off <<= 1) {
        int u = (t >= off) ? s[t - off] : 0;
        __syncthreads();
        s[t] += u;
        __syncthreads();
    }
    if (t <= NBUK) bstart[t] = s[t] - v;         // bstart[NBUK] = E
}

// ---------------- pass 3: placement, LDS-staged bucket sort, coalesced out ----

__global__ __launch_bounds__(256) void k_place(const int* __restrict__ row,
                                               const int* __restrict__ col,
                                               const float* __restrict__ ew,
                                               const int* __restrict__ offs,
                                               const int* __restrict__ bstart,
                                               int2* __restrict__ pay) {
    __shared__ int2 spay[EPB];                   // 25000 B
    __shared__ unsigned short sbuk[EPB];         // 6250 B
    __shared__ int lh[NBUK];                     // hist, then cursor
    __shared__ int gb[NBUK];                     // per-bucket global base
    __shared__ int sA[1024], sB[1024];           // scan buffers
    int tid = threadIdx.x, blk = blockIdx.x;
    for (int i = tid; i < NBUK; i += 256) lh[i] = 0;
    __syncthreads();
    int s0 = blk * EPB;
    // pass A: local histogram
    for (int j = tid; j < EPB; j += 256)
        atomicAdd(&lh[col[s0 + j] >> 7], 1);
    __syncthreads();
    // local inclusive scan of lh (padded to 1024)
    for (int i = tid; i < 1024; i += 256) sA[i] = (i < NBUK) ? lh[i] : 0;
    __syncthreads();
    int* src = sA; int* dst = sB;
    for (int off = 1; off < 1024; off <<= 1) {
        for (int i = tid; i < 1024; i += 256)
            dst[i] = src[i] + ((i >= off) ? src[i - off] : 0);
        __syncthreads();
        int* tmp = src; src = dst; dst = tmp;
    }
    // cursor = local exclusive; gb = global base minus local exclusive
    for (int i = tid; i < NBUK; i += 256) {
        int excl = src[i] - lh[i];
        gb[i] = bstart[i] + offs[i * NBLK + blk] - excl;
        lh[i] = excl;                            // reuse as arrival cursor
    }
    __syncthreads();
    // pass B: stage bucket-sorted into LDS
    for (int j = tid; j < EPB; j += 256) {
        int e = s0 + j;
        int c = col[e];
        int b = c >> 7;
        int pos = atomicAdd(&lh[b], 1);
        spay[pos] = make_int2(((c & 127) << 17) | row[e], __float_as_int(ew[e]));
        sbuk[pos] = (unsigned short)b;
    }
    __syncthreads();
    // write out: consecutive threads -> consecutive global positions per run
    for (int j = tid; j < EPB; j += 256) {
        int b = sbuk[j];
        pay[gb[b] + j] = spay[j];
    }
}

// ---------------- pass 4: in-bucket node sort (in place) + node_start + dinv --

__global__ __launch_bounds__(256) void k_sort2(const int* __restrict__ bstart,
                                               int2* __restrict__ pay,
                                               int* __restrict__ node_start,
                                               float* __restrict__ dinv) {
    __shared__ int2 buf[BUFCAP];
    __shared__ int cnt[BSH], sc[BSH], pos[BSH];
    __shared__ float dsum[BSH];
    int b = blockIdx.x, t = threadIdx.x;
    if (t < BSH) { cnt[t] = 0; dsum[t] = 1.0f; }   // 1.0 = self-loop weight
    __syncthreads();
    int s = bstart[b], e2 = bstart[b + 1];
    int m = e2 - s;
    for (int j = t; j < m; j += 256) {
        int2 pr = pay[s + j];
        buf[j] = pr;
        int d = pr.x >> 17;
        atomicAdd(&cnt[d], 1);
        atomicAdd(&dsum[d], __int_as_float(pr.y));
    }
    __syncthreads();
    int v = (t < BSH) ? cnt[t] : 0;
    if (t < BSH) sc[t] = v;
    __syncthreads();
    for (int off = 1; off < BSH; off <<= 1) {
        int u = (t >= off && t < BSH) ? sc[t - off] : 0;
        __syncthreads();
        if (t < BSH) sc[t] += u;
        __syncthreads();
    }
    if (t < BSH) {
        int excl = sc[t] - v;
        pos[t] = excl;
        int node = b * BSH + t;
        if (node <= N_NODES) node_start[node] = s + excl;
        if (node < N_NODES) dinv[node] = rsqrtf(dsum[t]);
    }
    if (t == 0 && b == 0) node_start[N_NODES] = N_EDGES;  // sentinel (exact)
    __syncthreads();
    for (int j = t; j < m; j += 256) {
        int2 pr = buf[j];
        int q = atomicAdd(&pos[pr.x >> 17], 1);
        pay[s + q] = make_int2(pr.x & 0x1FFFF, pr.y);     // strip dlow
    }
}

// ---------------- GEMM x@W1, epilogue x dinv: t1 = dinv ⊙ (x@W1) --------------

__global__ __launch_bounds__(256) void k_gemm_in(const float* __restrict__ x,
                                                 const float* __restrict__ W1,
                                                 const float* __restrict__ dinv,
                                                 float* __restrict__ t1) {
    __shared__ float ws[INC * HID];
    __shared__ float xs[16 * 129];
    int tid = threadIdx.x;
    int nb = blockIdx.x * 16;
    const float4* x4 = (const float4*)(x + (size_t)nb * INC);
    for (int j = tid; j < 512; j += 256) {
        float4 v = x4[j];
        int n = j >> 5, kq = (j & 31) << 2;
        float* d = &xs[n * 129 + kq];
        d[0] = v.x; d[1] = v.y; d[2] = v.z; d[3] = v.w;
    }
    for (int j = tid; j < 512; j += 256)
        ((float4*)ws)[j] = ((const float4*)W1)[j];
    __syncthreads();
    int ln = tid >> 4, c = tid & 15;
    float acc = 0.f;
#pragma unroll
    for (int k = 0; k < INC; ++k) acc += xs[ln * 129 + k] * ws[k * HID + c];
    int node = nb + ln;
    t1[(node << 4) + c] = dinv[node] * acc;
}

// ---------------- aggregation, one wave per node ----------------

__global__ __launch_bounds__(256) void k_agg_mid(const int* __restrict__ node_start,
                                                 const int2* __restrict__ pay,
                                                 const float* __restrict__ dinv,
                                                 const float* __restrict__ t1,
                                                 const float* __restrict__ b,
                                                 float* __restrict__ h) {
    int i = (blockIdx.x * 256 + threadIdx.x) >> 6;
    if (i >= N_NODES) return;
    int lane = threadIdx.x & 63;
    int eo = lane >> 4;
    int c  = lane & 15;
    int s = node_start[i], e2 = node_start[i + 1];
    float acc = 0.f;
    for (int p = s + eo; p < e2; p += 4) {
        int2 pr = pay[p];
        acc += __int_as_float(pr.y) * t1[((size_t)pr.x << 4) + c];
    }
    acc += __shfl_xor(acc, 16);
    acc += __shfl_xor(acc, 32);
    float v = dinv[i] * (acc + t1[((size_t)i << 4) + c]) + b[c];
    if (lane < 16) h[((size_t)i << 4) + c] = fmaxf(v, 0.f);
}

__global__ __launch_bounds__(256) void k_agg_out(const int* __restrict__ node_start,
                                                 const int2* __restrict__ pay,
                                                 const float* __restrict__ dinv,
                                                 const float* __restrict__ t2,
                                                 const float* __restrict__ b,
                                                 const float* __restrict__ Wout,
                                                 const float* __restrict__ bout,
                                                 float* __restrict__ out) {
    int i = (blockIdx.x * 256 + threadIdx.x) >> 6;
    if (i >= N_NODES) return;
    int lane = threadIdx.x & 63;
    int eo = lane >> 4;
    int c  = lane & 15;
    int s = node_start[i], e2 = node_start[i + 1];
    float acc = 0.f;
    for (int p = s + eo; p < e2; p += 4) {
        int2 pr = pay[p];
        acc += __int_as_float(pr.y) * t2[((size_t)pr.x << 4) + c];
    }
    acc += __shfl_xor(acc, 16);
    acc += __shfl_xor(acc, 32);
    float v = dinv[i] * (acc + t2[((size_t)i << 4) + c]) + b[c];
    float r = fmaxf(v, 0.f) * Wout[c];
#pragma unroll
    for (int m = 8; m >= 1; m >>= 1) r += __shfl_xor(r, m);
    if (lane == 0) out[i] = r + bout[0];
}

// ---------------- GEMM h@W2, epilogue x dinv ----------------

__global__ __launch_bounds__(256) void k_gemm_hid(const float* __restrict__ h,
                                                  const float* __restrict__ W,
                                                  const float* __restrict__ dinv,
                                                  float* __restrict__ t2) {
    __shared__ float ws[HID * HID];
    int tid = threadIdx.x;
    if (tid < HID * HID) ws[tid] = W[tid];
    __syncthreads();
    int idx = blockIdx.x * 256 + tid;
    if (idx >= N_NODES * HID) return;
    int i = idx >> 4, c = idx & 15;
    const float* hr = h + (size_t)i * HID;
    float acc = 0.f;
#pragma unroll
    for (int k = 0; k < HID; ++k) acc += hr[k] * ws[k * HID + c];
    t2[idx] = dinv[i] * acc;
}

extern "C" void kernel_launch(void* const* d_in, const int* in_sizes, int n_in,
                              void* d_out, int out_size, void* d_ws, size_t ws_size,
                              hipStream_t stream) {
    const float* x    = (const float*)d_in[0];
    const int*   eidx = (const int*)d_in[1];
    const float* ew   = (const float*)d_in[2];
    const float* W1   = (const float*)d_in[5];
    const float* b1   = (const float*)d_in[6];
    const float* W2   = (const float*)d_in[7];
    const float* b2   = (const float*)d_in[8];
    const float* Wout = (const float*)d_in[9];
    const float* bout = (const float*)d_in[10];
    float* out = (float*)d_out;

    const int* row = eidx;             // edge_index[0] (src)
    const int* col = eidx + N_EDGES;   // edge_index[1] (dst)

    // workspace (4B units). blkhist/offs alias t1/h (dead before GEMMs run).
    float* t1      = (float*)d_ws;                   // N*16 = 1.6M
    float* h       = t1 + (size_t)N_NODES * HID;     // N*16 = 1.6M
    int*   blkhist = (int*)d_ws;                     // NBLK*NBUK = 800768 (alias t1)
    int*   offs    = blkhist + NBLK * NBUK;          // 800768 (alias t1/h)
    int*   total   = (int*)(h + (size_t)N_NODES * HID);  // 784
    int*   bstart  = total + 784;                    // 784
    float* dinv    = (float*)(bstart + 784);         // N
    int*   nstart  = (int*)(dinv + N_NODES);         // N+4 (even pad)
    int2*  pay     = (int2*)(nstart + N_NODES + 4);  // E int2 (8B-aligned)

    float* t2 = t1;                                  // gemm_hid overwrites t1

    const int B = 256;
    const int gW = (N_NODES * 64 + B - 1) / B;       // 25000 (wave per node)

    // CSR build (two-level counting sort, no global atomics)
    k_hist1  <<<NBLK, B, 0, stream>>>(col, blkhist);
    k_colscan<<<NBUK, 1024, 0, stream>>>(blkhist, offs, total);
    k_bscan  <<<1, 1024, 0, stream>>>(total, bstart);
    k_place  <<<NBLK, B, 0, stream>>>(row, col, ew, offs, bstart, pay);
    k_sort2  <<<NBUK, B, 0, stream>>>(bstart, pay, nstart, dinv);

    // layer 1
    k_gemm_in<<<N_NODES / 16, B, 0, stream>>>(x, W1, dinv, t1);
    k_agg_mid<<<gW, B, 0, stream>>>(nstart, pay, dinv, t1, b1, h);

    // layer 2 (+ fused output projection)
    k_gemm_hid<<<(N_NODES * HID + B - 1) / B, B, 0, stream>>>(h, W2, dinv, t2);
    k_agg_out<<<gW, B, 0, stream>>>(nstart, pay, dinv, t2, b2, Wout, bout, out);
}

// Round 8
// 343.050 us; speedup vs baseline: 2.8051x; 1.2658x over previous
//
#include <hip/hip_runtime.h>
#include <hip/hip_bf16.h>

// GCN forward — two-level counting-sort CSR (no global atomics, coalesced
// placement) + float4-quadrant wave-per-node gather aggregation (16 rows in
// flight per wave), h@W2 fused into layer-1 aggregation epilogue.
// N=100000, E=3200000, IN_C=128, HID=16, OUT=1.

constexpr int N_NODES = 100000;
constexpr int N_EDGES = 3200000;
constexpr int INC = 128;
constexpr int HID = 16;

constexpr int BSH  = 128;                       // nodes per bucket
constexpr int NBUK = (N_NODES + BSH - 1) / BSH; // 782
constexpr int NBLK = 1024;                      // edge-chunk blocks
constexpr int EPB  = N_EDGES / NBLK;            // 3125 edges/block (exact)
constexpr int BUFCAP = 6144;                    // LDS edge staging in sort2

// ---------------- pass 1: per-block LDS histogram (block-major out) -----------

__global__ __launch_bounds__(256) void k_hist1(const int* __restrict__ col,
                                               int* __restrict__ blkhist) {
    __shared__ int lh[NBUK];
    int tid = threadIdx.x, blk = blockIdx.x;
    for (int i = tid; i < NBUK; i += 256) lh[i] = 0;
    __syncthreads();
    int s = blk * EPB;
    for (int e = s + tid; e < s + EPB; e += 256)
        atomicAdd(&lh[col[e] >> 7], 1);          // LDS atomic
    __syncthreads();
    for (int i = tid; i < NBUK; i += 256)
        blkhist[blk * NBUK + i] = lh[i];         // coalesced
}

// ---------------- pass 2a: per-bucket scan over the 1024 block counts ---------

__global__ __launch_bounds__(1024) void k_colscan(const int* __restrict__ blkhist,
                                                  int* __restrict__ offs,
                                                  int* __restrict__ total) {
    __shared__ int sA[NBLK], sB[NBLK];
    int b = blockIdx.x, t = threadIdx.x;
    int v = blkhist[t * NBUK + b];
    sA[t] = v;
    __syncthreads();
    int* src = sA; int* dst = sB;
    for (int off = 1; off < NBLK; off <<= 1) {
        dst[t] = src[t] + ((t >= off) ? src[t - off] : 0);
        __syncthreads();
        int* tmp = src; src = dst; dst = tmp;
    }
    offs[b * NBLK + t] = src[t] - v;
    if (t == NBLK - 1) total[b] = src[NBLK - 1];
}

// ---------------- pass 2b: bucket starts (single block) ----------------

__global__ __launch_bounds__(1024) void k_bscan(const int* __restrict__ total,
                                                int* __restrict__ bstart) {
    __shared__ int s[1024];
    int t = threadIdx.x;
    int v = (t < NBUK) ? total[t] : 0;
    s[t] = v;
    __syncthreads();
    for (int off = 1; off < 1024; off <<= 1) {
        int u = (t >= off) ? s[t - off] : 0;
        __syncthreads();
        s[t] += u;
        __syncthreads();
    }
    if (t <= NBUK) bstart[t] = s[t] - v;         // bstart[NBUK] = E
}

// ---------------- pass 3: placement, LDS-staged bucket sort, coalesced out ----

__global__ __launch_bounds__(256) void k_place(const int* __restrict__ row,
                                               const int* __restrict__ col,
                                               const float* __restrict__ ew,
                                               const int* __restrict__ offs,
                                               const int* __restrict__ bstart,
                                               int2* __restrict__ pay) {
    __shared__ int2 spay[EPB];
    __shared__ unsigned short sbuk[EPB];
    __shared__ int lh[NBUK];
    __shared__ int gb[NBUK];
    __shared__ int sA[1024], sB[1024];
    int tid = threadIdx.x, blk = blockIdx.x;
    for (int i = tid; i < NBUK; i += 256) lh[i] = 0;
    __syncthreads();
    int s0 = blk * EPB;
    for (int j = tid; j < EPB; j += 256)
        atomicAdd(&lh[col[s0 + j] >> 7], 1);
    __syncthreads();
    for (int i = tid; i < 1024; i += 256) sA[i] = (i < NBUK) ? lh[i] : 0;
    __syncthreads();
    int* src = sA; int* dst = sB;
    for (int off = 1; off < 1024; off <<= 1) {
        for (int i = tid; i < 1024; i += 256)
            dst[i] = src[i] + ((i >= off) ? src[i - off] : 0);
        __syncthreads();
        int* tmp = src; src = dst; dst = tmp;
    }
    for (int i = tid; i < NBUK; i += 256) {
        int excl = src[i] - lh[i];
        gb[i] = bstart[i] + offs[i * NBLK + blk] - excl;
        lh[i] = excl;
    }
    __syncthreads();
    for (int j = tid; j < EPB; j += 256) {
        int e = s0 + j;
        int c = col[e];
        int b = c >> 7;
        int pos = atomicAdd(&lh[b], 1);
        spay[pos] = make_int2(((c & 127) << 17) | row[e], __float_as_int(ew[e]));
        sbuk[pos] = (unsigned short)b;
    }
    __syncthreads();
    for (int j = tid; j < EPB; j += 256) {
        int b = sbuk[j];
        pay[gb[b] + j] = spay[j];
    }
}

// ---------------- pass 4: in-bucket node sort (in place) + node_start + dinv --

__global__ __launch_bounds__(256) void k_sort2(const int* __restrict__ bstart,
                                               int2* __restrict__ pay,
                                               int* __restrict__ node_start,
                                               float* __restrict__ dinv) {
    __shared__ int2 buf[BUFCAP];
    __shared__ int cnt[BSH], sc[BSH], pos[BSH];
    __shared__ float dsum[BSH];
    int b = blockIdx.x, t = threadIdx.x;
    if (t < BSH) { cnt[t] = 0; dsum[t] = 1.0f; }   // 1.0 = self-loop weight
    __syncthreads();
    int s = bstart[b], e2 = bstart[b + 1];
    int m = e2 - s;
    for (int j = t; j < m; j += 256) {
        int2 pr = pay[s + j];
        buf[j] = pr;
        int d = pr.x >> 17;
        atomicAdd(&cnt[d], 1);
        atomicAdd(&dsum[d], __int_as_float(pr.y));
    }
    __syncthreads();
    int v = (t < BSH) ? cnt[t] : 0;
    if (t < BSH) sc[t] = v;
    __syncthreads();
    for (int off = 1; off < BSH; off <<= 1) {
        int u = (t >= off && t < BSH) ? sc[t - off] : 0;
        __syncthreads();
        if (t < BSH) sc[t] += u;
        __syncthreads();
    }
    if (t < BSH) {
        int excl = sc[t] - v;
        pos[t] = excl;
        int node = b * BSH + t;
        if (node <= N_NODES) node_start[node] = s + excl;
        if (node < N_NODES) dinv[node] = rsqrtf(dsum[t]);
    }
    if (t == 0 && b == 0) node_start[N_NODES] = N_EDGES;
    __syncthreads();
    for (int j = t; j < m; j += 256) {
        int2 pr = buf[j];
        int q = atomicAdd(&pos[pr.x >> 17], 1);
        pay[s + q] = make_int2(pr.x & 0x1FFFF, pr.y);
    }
}

// ---------------- GEMM x@W1, epilogue x dinv: t1 = dinv ⊙ (x@W1) --------------

__global__ __launch_bounds__(256) void k_gemm_in(const float* __restrict__ x,
                                                 const float* __restrict__ W1,
                                                 const float* __restrict__ dinv,
                                                 float* __restrict__ t1) {
    __shared__ float ws[INC * HID];
    __shared__ float xs[16 * 129];
    int tid = threadIdx.x;
    int nb = blockIdx.x * 16;
    const float4* x4 = (const float4*)(x + (size_t)nb * INC);
    for (int j = tid; j < 512; j += 256) {
        float4 v = x4[j];
        int n = j >> 5, kq = (j & 31) << 2;
        float* d = &xs[n * 129 + kq];
        d[0] = v.x; d[1] = v.y; d[2] = v.z; d[3] = v.w;
    }
    for (int j = tid; j < 512; j += 256)
        ((float4*)ws)[j] = ((const float4*)W1)[j];
    __syncthreads();
    int ln = tid >> 4, c = tid & 15;
    float acc = 0.f;
#pragma unroll
    for (int k = 0; k < INC; ++k) acc += xs[ln * 129 + k] * ws[k * HID + c];
    int node = nb + ln;
    t1[(node << 4) + c] = dinv[node] * acc;
}

// ---------------- layer-1 aggregation + bias/relu + fused h@W2 -> t2 ----------
// wave per node; lanes = 16 edge-slots x 4 float4-quadrants (16 rows in flight)

__global__ __launch_bounds__(256) void k_agg_mid(const int* __restrict__ node_start,
                                                 const int2* __restrict__ pay,
                                                 const float* __restrict__ dinv,
                                                 const float* __restrict__ t1,
                                                 const float* __restrict__ bias,
                                                 const float* __restrict__ W2,
                                                 float* __restrict__ t2) {
    __shared__ float w2s[HID * HID];
    int tid = threadIdx.x;
    w2s[tid] = W2[tid];
    __syncthreads();
    int i = (blockIdx.x * 256 + tid) >> 6;       // node id (grid exact: no oob)
    int lane = tid & 63;
    int eg = lane >> 2, q = lane & 3;
    int s = node_start[i], e2 = node_start[i + 1];
    const float4* t4 = (const float4*)t1;
    float4 acc = make_float4(0.f, 0.f, 0.f, 0.f);
    for (int p = s + eg; p < e2; p += 16) {
        int2 pr = pay[p];
        float w = __int_as_float(pr.y);
        float4 v = t4[(pr.x << 2) + q];
        acc.x += w * v.x; acc.y += w * v.y; acc.z += w * v.z; acc.w += w * v.w;
    }
#pragma unroll
    for (int m = 4; m <= 32; m <<= 1) {
        acc.x += __shfl_xor(acc.x, m);
        acc.y += __shfl_xor(acc.y, m);
        acc.z += __shfl_xor(acc.z, m);
        acc.w += __shfl_xor(acc.w, m);
    }
    float d = dinv[i];
    float4 self = t4[(i << 2) + q];
    float4 bb = ((const float4*)bias)[q];
    float4 hv;
    hv.x = fmaxf(d * (acc.x + self.x) + bb.x, 0.f);
    hv.y = fmaxf(d * (acc.y + self.y) + bb.y, 0.f);
    hv.z = fmaxf(d * (acc.z + self.z) + bb.z, 0.f);
    hv.w = fmaxf(d * (acc.w + self.w) + bb.w, 0.f);
    // broadcast full h row (lane j holds quadrant j for j=0..3)
    float hk[16];
#pragma unroll
    for (int j = 0; j < 4; ++j) {
        hk[j * 4 + 0] = __shfl(hv.x, j);
        hk[j * 4 + 1] = __shfl(hv.y, j);
        hk[j * 4 + 2] = __shfl(hv.z, j);
        hk[j * 4 + 3] = __shfl(hv.w, j);
    }
    if (lane < 16) {
        float acc2 = 0.f;
#pragma unroll
        for (int k = 0; k < HID; ++k) acc2 += hk[k] * w2s[k * HID + lane];
        t2[(i << 4) + lane] = d * acc2;
    }
}

// ---------------- layer-2 aggregation + bias/relu + Wout dot -> out -----------

__global__ __launch_bounds__(256) void k_agg_out(const int* __restrict__ node_start,
                                                 const int2* __restrict__ pay,
                                                 const float* __restrict__ dinv,
                                                 const float* __restrict__ t2,
                                                 const float* __restrict__ bias,
                                                 const float* __restrict__ Wout,
                                                 const float* __restrict__ bout,
                                                 float* __restrict__ out) {
    int tid = threadIdx.x;
    int i = (blockIdx.x * 256 + tid) >> 6;
    int lane = tid & 63;
    int eg = lane >> 2, q = lane & 3;
    int s = node_start[i], e2 = node_start[i + 1];
    const float4* t4 = (const float4*)t2;
    float4 acc = make_float4(0.f, 0.f, 0.f, 0.f);
    for (int p = s + eg; p < e2; p += 16) {
        int2 pr = pay[p];
        float w = __int_as_float(pr.y);
        float4 v = t4[(pr.x << 2) + q];
        acc.x += w * v.x; acc.y += w * v.y; acc.z += w * v.z; acc.w += w * v.w;
    }
#pragma unroll
    for (int m = 4; m <= 32; m <<= 1) {
        acc.x += __shfl_xor(acc.x, m);
        acc.y += __shfl_xor(acc.y, m);
        acc.z += __shfl_xor(acc.z, m);
        acc.w += __shfl_xor(acc.w, m);
    }
    float d = dinv[i];
    float4 self = t4[(i << 2) + q];
    float4 bb = ((const float4*)bias)[q];
    float4 wo = ((const float4*)Wout)[q];
    float r = fmaxf(d * (acc.x + self.x) + bb.x, 0.f) * wo.x
            + fmaxf(d * (acc.y + self.y) + bb.y, 0.f) * wo.y
            + fmaxf(d * (acc.z + self.z) + bb.z, 0.f) * wo.z
            + fmaxf(d * (acc.w + self.w) + bb.w, 0.f) * wo.w;
    r += __shfl_xor(r, 1);
    r += __shfl_xor(r, 2);
    if (lane == 0) out[i] = r + bout[0];
}

extern "C" void kernel_launch(void* const* d_in, const int* in_sizes, int n_in,
                              void* d_out, int out_size, void* d_ws, size_t ws_size,
                              hipStream_t stream) {
    const float* x    = (const float*)d_in[0];
    const int*   eidx = (const int*)d_in[1];
    const float* ew   = (const float*)d_in[2];
    const float* W1   = (const float*)d_in[5];
    const float* b1   = (const float*)d_in[6];
    const float* W2   = (const float*)d_in[7];
    const float* b2   = (const float*)d_in[8];
    const float* Wout = (const float*)d_in[9];
    const float* bout = (const float*)d_in[10];
    float* out = (float*)d_out;

    const int* row = eidx;             // edge_index[0] (src)
    const int* col = eidx + N_EDGES;   // edge_index[1] (dst)

    // workspace (4B units). blkhist/offs alias t1/t2 (dead before GEMM runs).
    float* t1      = (float*)d_ws;                   // N*16 = 1.6M
    float* t2      = t1 + (size_t)N_NODES * HID;     // N*16 = 1.6M
    int*   blkhist = (int*)d_ws;                     // NBLK*NBUK = 800768 (alias)
    int*   offs    = blkhist + NBLK * NBUK;          // 800768 (alias)
    int*   total   = (int*)(t2 + (size_t)N_NODES * HID); // 784
    int*   bstart  = total + 784;                    // 784
    float* dinv    = (float*)(bstart + 784);         // N
    int*   nstart  = (int*)(dinv + N_NODES);         // N+4 (even pad)
    int2*  pay     = (int2*)(nstart + N_NODES + 4);  // E int2 (8B-aligned)

    const int B = 256;
    const int gW = (N_NODES * 64) / B;               // 25000 exact (wave/node)

    // CSR build (two-level counting sort, no global atomics)
    k_hist1  <<<NBLK, B, 0, stream>>>(col, blkhist);
    k_colscan<<<NBUK, 1024, 0, stream>>>(blkhist, offs, total);
    k_bscan  <<<1, 1024, 0, stream>>>(total, bstart);
    k_place  <<<NBLK, B, 0, stream>>>(row, col, ew, offs, bstart, pay);
    k_sort2  <<<NBUK, B, 0, stream>>>(bstart, pay, nstart, dinv);

    // layer 1 GEMM (+dinv epilogue)
    k_gemm_in<<<N_NODES / 16, B, 0, stream>>>(x, W1, dinv, t1);

    // layer 1 aggregation + relu + fused h@W2 (+dinv epilogue)
    k_agg_mid<<<gW, B, 0, stream>>>(nstart, pay, dinv, t1, b1, W2, t2);

    // layer 2 aggregation + relu + fused output projection
    k_agg_out<<<gW, B, 0, stream>>>(nstart, pay, dinv, t2, b2, Wout, bout, out);
}